// Round 4
// baseline (349.304 us; speedup 1.0000x reference)
//
#include <hip/hip_runtime.h>

// ConvAttention fused pipeline for MI355X (gfx950), round 3 (resubmit — r3 never ran).
//
// Pipeline (6 dispatches):
//  kprep  : fold BN into pointwise weights; Wmix/beta; out_w -> bf16 hi/lo; zero vsum+lsum
//  kqkv   : depthwise 3x3 + folded BN + 8x8 pointwise -> q (bf16, scale*log2e folded),
//           k (bf16), v (bf16)
//  kvtrans: v bf16 [b,h,n,d] -> vT [b,h,d,n] + V row-sum partials (atomicAdd)
//  kl     : lsum[b,c,i] = sum_j 2^(S') via K-stationary MFMA sweep (LDS+global atomics)
//  kattn2 : barrier-free main loop; wave = j-slice, computes S^T for ALL 8 heads,
//           in-register cross-head mix, wave-local LDS quad->A-frag shuffle, PV MFMA;
//           cross-wave O reduce in epilogue. O written as bf16 hi/lo.
//  kout   : [8192,512]x[512,512]^T projection, bf16 MFMA hi/lo 3-product split

#define EPS 1e-5f
#define SCALE2 0.510138584f  // H^-0.5 * log2(e): softmax in base 2

typedef float f32x4 __attribute__((ext_vector_type(4)));
typedef short short8 __attribute__((ext_vector_type(8)));
typedef unsigned short ushort;

#define MFMA16(a, b, c) __builtin_amdgcn_mfma_f32_16x16x32_bf16(a, b, c, 0, 0, 0)

__device__ __forceinline__ unsigned short f2bf(float f) {
  union { float f; unsigned u; } v; v.f = f;
  return (unsigned short)((v.u + 0x7FFFu + ((v.u >> 16) & 1u)) >> 16);
}
__device__ __forceinline__ float bf2f(unsigned short h) {
  union { unsigned u; float f; } v; v.u = ((unsigned)h) << 16;
  return v.f;
}
__device__ __forceinline__ int cvtpk(float lo, float hi) {
  int r;
  asm("v_cvt_pk_bf16_f32 %0, %1, %2" : "=v"(r) : "v"(lo), "v"(hi));
  return r;
}

// ---------------------------------------------------------------- kprep
__global__ __launch_bounds__(256) void kprep(
    const float* __restrict__ dwb, const float* __restrict__ bng,
    const float* __restrict__ bnb, const float* __restrict__ bnm,
    const float* __restrict__ bnv, const float* __restrict__ pww,
    const float* __restrict__ pwb, const float* __restrict__ rew,
    const float* __restrict__ reb, const float* __restrict__ vng,
    const float* __restrict__ vnb, const float* __restrict__ vnm,
    const float* __restrict__ vnv, const float* __restrict__ outw,
    float* __restrict__ smalls, float* __restrict__ vsum,
    float* __restrict__ lsum, ushort* __restrict__ wh,
    ushort* __restrict__ wl) {
  int g = blockIdx.x * 256 + threadIdx.x;
  if (g < 262144) {
    float v = outw[g];
    ushort hi = f2bf(v);
    wh[g] = hi;
    wl[g] = f2bf(v - bf2f(hi));
  }
  if (blockIdx.x >= 1 && blockIdx.x <= 16)
    vsum[(blockIdx.x - 1) * 256 + threadIdx.x] = 0.f;
  if (blockIdx.x >= 17 && blockIdx.x <= 272)
    lsum[(blockIdx.x - 17) * 256 + threadIdx.x] = 0.f;
  if (blockIdx.x == 0) {
    int t = threadIdx.x;
    if (t < 64) {  // Wmix[o][c]
      int o = t >> 3, c = t & 7;
      float s = vng[o] * rsqrtf(vnv[o] + EPS);
      smalls[t] = rew[o * 8 + c] * s;
    }
    if (t < 8) {   // beta[o]
      float s = vng[t] * rsqrtf(vnv[t] + EPS);
      smalls[64 + t] = (reb[t] - vnm[t]) * s + vnb[t];
    }
    if (t < 192) { // pw_eff[p][o][c]
      int p = t >> 6, rem = t & 63, o = rem >> 3, c = rem & 7;
      float s = bng[p * 8 + c] * rsqrtf(bnv[p * 8 + c] + EPS);
      smalls[72 + t] = pww[(p * 8 + o) * 8 + c] * s;
    }
    if (t < 24) {  // pwb_eff[p][o]
      int p = t / 8, o = t & 7;
      float acc = pwb[p * 8 + o];
      for (int c = 0; c < 8; ++c) {
        float s = bng[p * 8 + c] * rsqrtf(bnv[p * 8 + c] + EPS);
        acc += pww[(p * 8 + o) * 8 + c] *
               ((dwb[p * 8 + c] - bnm[p * 8 + c]) * s + bnb[p * 8 + c]);
      }
      smalls[264 + t] = acc;
    }
  }
}

// ---------------------------------------------------------------- kqkv
__global__ __launch_bounds__(256) void kqkv(
    const float* __restrict__ x, const float* __restrict__ dww,
    const float* __restrict__ smalls,
    ushort* __restrict__ qb, ushort* __restrict__ kb,
    ushort* __restrict__ vb) {
  int t = threadIdx.x;
  int blk = blockIdx.x;
  int b = blk >> 8;
  int n0 = (blk & 255) << 2;
  int d = t & 63;
  int n = n0 + (t >> 6);
  const float* pw_eff = smalls + 72;
  const float* pwb_eff = smalls + 264;
  float y[3][8];
  for (int h = 0; h < 8; ++h) {
    float nb[3][3];
#pragma unroll
    for (int ky = 0; ky < 3; ++ky) {
      int nn = n - 1 + ky;
      bool vr = (nn >= 0) && (nn < 1024);
      const float* xp = x + ((b * 1024 + nn) * 512 + h * 64 + d);
      nb[ky][0] = (vr && d > 0) ? xp[-1] : 0.f;
      nb[ky][1] = vr ? xp[0] : 0.f;
      nb[ky][2] = (vr && d < 63) ? xp[1] : 0.f;
    }
#pragma unroll
    for (int p = 0; p < 3; ++p) {
      const float* w = dww + (p * 8 + h) * 9;
      float a = 0.f;
#pragma unroll
      for (int ky = 0; ky < 3; ++ky)
#pragma unroll
        for (int kx = 0; kx < 3; ++kx) a += w[ky * 3 + kx] * nb[ky][kx];
      y[p][h] = a;
    }
  }
#pragma unroll
  for (int p = 0; p < 3; ++p) {
#pragma unroll
    for (int o = 0; o < 8; ++o) {
      float a = pwb_eff[p * 8 + o];
#pragma unroll
      for (int c = 0; c < 8; ++c) a += pw_eff[p * 64 + o * 8 + c] * y[p][c];
      int idx = ((b * 8 + o) * 1024 + n) * 64 + d;
      if (p == 0) qb[idx] = f2bf(a * SCALE2);
      else if (p == 1) kb[idx] = f2bf(a);
      else vb[idx] = f2bf(a);
    }
  }
}

// ---------------------------------------------------------------- kvtrans (+vsum)
__global__ __launch_bounds__(256) void kvtrans(const ushort* __restrict__ vb,
                                               ushort* __restrict__ vt,
                                               float* __restrict__ vsum) {
  __shared__ ushort lds[64 * 65];
  __shared__ float red[256];
  int bh = blockIdx.x >> 4;
  int nt = blockIdx.x & 15;
  int t = threadIdx.x;
  const ushort* src = vb + (bh * 1024 + nt * 64) * 64;
  float part = 0.f;
#pragma unroll
  for (int it = 0; it < 16; ++it) {
    int nn = (t >> 6) + it * 4;
    int d = t & 63;
    ushort v = src[nn * 64 + d];
    part += bf2f(v);
    lds[nn * 65 + d] = v;
  }
  red[t] = part;
  __syncthreads();
  ushort* dst = vt + bh * 64 * 1024 + nt * 64;
#pragma unroll
  for (int it = 0; it < 16; ++it) {
    int d = (t >> 6) + it * 4;
    int n = t & 63;
    dst[d * 1024 + n] = lds[n * 65 + d];
  }
  if (t < 64)
    atomicAdd(&vsum[bh * 64 + t],
              red[t] + red[64 + t] + red[128 + t] + red[192 + t]);
}

// ---------------------------------------------------------------- kl
// lsum[b,c,i] = sum_j 2^(q_i . k_j). Block = (b, c, j-quarter); 8 waves x 32 j.
__global__ __launch_bounds__(512) void kl(const ushort* __restrict__ qb,
                                          const ushort* __restrict__ kb,
                                          float* __restrict__ lsum) {
  __shared__ float lacc[1024];
  int b = blockIdx.x & 7;
  int c = (blockIdx.x >> 3) & 7;
  int jq = blockIdx.x >> 6;
  int tid = threadIdx.x;
  int w = tid >> 6, l = tid & 63;
  int lrow = l & 15, lgrp = l >> 4;
  lacc[tid] = 0.f;
  lacc[tid + 512] = 0.f;
  __syncthreads();
  const ushort* kh = kb + ((b * 8 + c) * 1024 + jq * 256 + w * 32) * 64;
  short8 Kf[2][2];
#pragma unroll
  for (int jf = 0; jf < 2; ++jf)
#pragma unroll
    for (int kc = 0; kc < 2; ++kc)
      Kf[jf][kc] = *(const short8*)(kh + (jf * 16 + lrow) * 64 + kc * 32 + lgrp * 8);
  const ushort* qh = qb + (b * 8 + c) * 65536;
  for (int ci = 0; ci < 64; ++ci) {
    f32x4 a0 = {}, a1 = {};
#pragma unroll
    for (int kc = 0; kc < 2; ++kc) {
      short8 Qf = *(const short8*)(qh + (ci * 16 + lrow) * 64 + kc * 32 + lgrp * 8);
      a0 = MFMA16(Kf[0][kc], Qf, a0);
      a1 = MFMA16(Kf[1][kc], Qf, a1);
    }
    float s = 0.f;
#pragma unroll
    for (int r = 0; r < 4; ++r) s += exp2f(a0[r]) + exp2f(a1[r]);
    s += __shfl_xor(s, 16);
    s += __shfl_xor(s, 32);
    if (lgrp == 0) atomicAdd(&lacc[ci * 16 + lrow], s);
  }
  __syncthreads();
  atomicAdd(&lsum[(b * 8 + c) * 1024 + tid], lacc[tid]);
  atomicAdd(&lsum[(b * 8 + c) * 1024 + 512 + tid], lacc[512 + tid]);
}

// ---------------------------------------------------------------- kattn2
// Block = (b, 16-row i-tile), 8 waves = 8 j-slices (128 j each). No main-loop barriers.
// Per wave, per 16j sub-chunk: S^T = MFMA(Kfrag, Qfrag) per head (C: i=lane&15,
// j=lgrp*4+r), p = 2^S * linv, in-register mix over heads -> quad pack -> wave-local
// swizzled LDS -> A-frag (i=lane&15, k=lgrp*8..+8) -> PV MFMA every 32 j.
__global__ __launch_bounds__(512, 2) void kattn2(
    const ushort* __restrict__ qb, const ushort* __restrict__ kb,
    const ushort* __restrict__ vt, const float* __restrict__ smalls,
    const float* __restrict__ vsum, const float* __restrict__ lsum,
    ushort* __restrict__ ohi, ushort* __restrict__ olo) {
  __shared__ ushort qlds[8192];           // 16KB [c][16i][64d] swizzled
  __shared__ ushort scr[8 * 8 * 16 * 32]; // 128KB [w][o][16i][32 jslot] swizzled
  int b = blockIdx.x & 7;
  int it = blockIdx.x >> 3;
  int i0 = it * 16;
  int tid = threadIdx.x;
  int w = tid >> 6, l = tid & 63;
  int lrow = l & 15, lgrp = l >> 4;

  // stage Q (all 8 heads, 16 rows) into swizzled LDS
  {
    int e = tid * 16;
    int c = e >> 10, i = (e >> 6) & 15, d0 = e & 63;
    const ushort* src = qb + ((b * 8 + c) * 1024 + i0 + i) * 64 + d0;
    int sw = (i & 7) << 3;
    *(short8*)&qlds[c * 1024 + i * 64 + (d0 ^ sw)] = *(const short8*)src;
    *(short8*)&qlds[c * 1024 + i * 64 + ((d0 + 8) ^ sw)] = *(const short8*)(src + 8);
  }
  __syncthreads();

  float Wc[64];
#pragma unroll
  for (int z = 0; z < 64; ++z)
    Wc[z] = __builtin_bit_cast(
        float, __builtin_amdgcn_readfirstlane(
                   __builtin_bit_cast(int, smalls[z])));

  float linv[8];
#pragma unroll
  for (int c = 0; c < 8; ++c)
    linv[c] = 1.0f / lsum[(b * 8 + c) * 1024 + i0 + lrow];

  const ushort* kh = kb + b * 8 * 65536;
  const ushort* vh = vt + b * 8 * 65536;
  int qsw = (lrow & 7) << 3;   // qlds read swizzle
  int ssw = (lrow & 3) << 3;   // scratch swizzle (bits 3-4)
  int sbase = (w * 8) * 512 + lrow * 32;  // scr element base for (w, o=0, lrow)

  f32x4 Oacc[8][4] = {};  // [o][nq]: i = lgrp*4+r, d = nq*16+lrow

  for (int ch = 0; ch < 4; ++ch) {
    int jb = w * 128 + ch * 32;
#pragma unroll
    for (int sub = 0; sub < 2; ++sub) {
      int js = jb + sub * 16;
      float m[8][4];
#pragma unroll
      for (int c = 0; c < 8; ++c) {
        f32x4 acc = {};
#pragma unroll
        for (int kc = 0; kc < 2; ++kc) {
          short8 Kf = *(const short8*)(kh + c * 65536 + (js + lrow) * 64 +
                                       kc * 32 + lgrp * 8);
          short8 Qf = *(const short8*)&qlds[c * 1024 + lrow * 64 +
                                            ((kc * 32 + lgrp * 8) ^ qsw)];
          acc = MFMA16(Kf, Qf, acc);
        }
        float p[4];
#pragma unroll
        for (int r = 0; r < 4; ++r) p[r] = exp2f(acc[r]) * linv[c];
#pragma unroll
        for (int o = 0; o < 8; ++o)
#pragma unroll
          for (int r = 0; r < 4; ++r) {
            if (c == 0) m[o][r] = Wc[o * 8] * p[r];
            else        m[o][r] += Wc[o * 8 + c] * p[r];
          }
      }
      int slot = (sub * 16 + lgrp * 4) ^ ssw;
#pragma unroll
      for (int o = 0; o < 8; ++o) {
        int w0 = cvtpk(m[o][0], m[o][1]);
        int w1 = cvtpk(m[o][2], m[o][3]);
        *(int2*)&scr[sbase + o * 512 + slot] = (int2){w0, w1};
      }
    }
    // PV over this 32-j chunk
    int rslot = (lgrp * 8) ^ ssw;
#pragma unroll
    for (int o = 0; o < 8; ++o) {
      short8 Af = *(const short8*)&scr[sbase + o * 512 + rslot];
#pragma unroll
      for (int nq = 0; nq < 4; ++nq) {
        short8 Vf = *(const short8*)(vh + o * 65536 + (nq * 16 + lrow) * 1024 +
                                     jb + lgrp * 8);
        Oacc[o][nq] = MFMA16(Af, Vf, Oacc[o][nq]);
      }
    }
  }

  __syncthreads();  // all scratch use done; reuse as f32 reduce buffer
  float* red = (float*)scr;  // 32KB: [w][16i][64d]
#pragma unroll
  for (int o = 0; o < 8; ++o) {
#pragma unroll
    for (int nq = 0; nq < 4; ++nq)
#pragma unroll
      for (int r = 0; r < 4; ++r)
        red[w * 1024 + (lgrp * 4 + r) * 64 + nq * 16 + lrow] = Oacc[o][nq][r];
    __syncthreads();
#pragma unroll
    for (int e = 0; e < 2; ++e) {
      int pos = tid + e * 512;
      int i = pos >> 6, d = pos & 63;
      float s = 0.f;
#pragma unroll
      for (int ww = 0; ww < 8; ++ww) s += red[ww * 1024 + pos];
      s += smalls[64 + o] * vsum[(b * 8 + o) * 64 + d];
      int idx = (b * 1024 + i0 + i) * 512 + o * 64 + d;
      ushort hi = f2bf(s);
      ohi[idx] = hi;
      olo[idx] = f2bf(s - bf2f(hi));
    }
    __syncthreads();
  }
}

// ---------------------------------------------------------------- kout
__global__ __launch_bounds__(256) void kout(
    const ushort* __restrict__ ohi, const ushort* __restrict__ olo,
    const ushort* __restrict__ wh, const ushort* __restrict__ wl,
    const float* __restrict__ outb, float* __restrict__ out) {
  int w = threadIdx.x >> 6, l = threadIdx.x & 63;
  int lrow = l & 15, lgrp = l >> 4;
  int i0 = blockIdx.x * 128 + w * 32;
  int n0 = blockIdx.y * 64;
  f32x4 acc[2][4] = {};
  for (int kc = 0; kc < 16; ++kc) {
    short8 Ah[2], Al[2], Bh[4], Bl[4];
#pragma unroll
    for (int a = 0; a < 2; ++a) {
      int ro = (i0 + a * 16 + lrow) * 512 + kc * 32 + lgrp * 8;
      Ah[a] = *(const short8*)(ohi + ro);
      Al[a] = *(const short8*)(olo + ro);
    }
#pragma unroll
    for (int nq = 0; nq < 4; ++nq) {
      int ro = (n0 + nq * 16 + lrow) * 512 + kc * 32 + lgrp * 8;
      Bh[nq] = *(const short8*)(wh + ro);
      Bl[nq] = *(const short8*)(wl + ro);
    }
#pragma unroll
    for (int a = 0; a < 2; ++a)
#pragma unroll
      for (int nq = 0; nq < 4; ++nq) {
        acc[a][nq] = MFMA16(Ah[a], Bh[nq], acc[a][nq]);
        acc[a][nq] = MFMA16(Ah[a], Bl[nq], acc[a][nq]);
        acc[a][nq] = MFMA16(Al[a], Bh[nq], acc[a][nq]);
      }
  }
#pragma unroll
  for (int a = 0; a < 2; ++a)
#pragma unroll
    for (int nq = 0; nq < 4; ++nq)
#pragma unroll
      for (int r = 0; r < 4; ++r) {
        int row = i0 + a * 16 + lgrp * 4 + r;
        int n = n0 + nq * 16 + lrow;
        out[row * 512 + n] = acc[a][nq][r] + outb[n];
      }
}

// ---------------------------------------------------------------- launch
extern "C" void kernel_launch(void* const* d_in, const int* in_sizes, int n_in,
                              void* d_out, int out_size, void* d_ws, size_t ws_size,
                              hipStream_t stream) {
  const float* x   = (const float*)d_in[0];
  const float* dww = (const float*)d_in[1];
  const float* dwb = (const float*)d_in[2];
  const float* bng = (const float*)d_in[3];
  const float* bnb = (const float*)d_in[4];
  const float* bnm = (const float*)d_in[5];
  const float* bnv = (const float*)d_in[6];
  const float* pww = (const float*)d_in[7];
  const float* pwb = (const float*)d_in[8];
  const float* rew = (const float*)d_in[9];
  const float* reb = (const float*)d_in[10];
  const float* vng = (const float*)d_in[11];
  const float* vnb = (const float*)d_in[12];
  const float* vnm = (const float*)d_in[13];
  const float* vnv = (const float*)d_in[14];
  const float* outw = (const float*)d_in[15];
  const float* outb = (const float*)d_in[16];

  char* ws = (char*)d_ws;
  const size_t MB = 1024 * 1024;
  ushort* qb  = (ushort*)(ws);
  ushort* kb  = (ushort*)(ws + 8 * MB);
  ushort* vt  = (ushort*)(ws + 16 * MB);
  ushort* vb  = (ushort*)(ws + 24 * MB);
  ushort* ohi = (ushort*)(ws + 32 * MB);
  ushort* olo = (ushort*)(ws + 40 * MB);
  ushort* wh  = (ushort*)(ws + 48 * MB);
  ushort* wl  = (ushort*)(ws + 48 * MB + 512 * 1024);
  float* smalls = (float*)(ws + 49 * MB);
  float* vsum   = (float*)(ws + 49 * MB + 4096);
  float* lsum   = (float*)(ws + 49 * MB + 8192 + 16384);

  hipLaunchKernelGGL(kprep, dim3(1024), dim3(256), 0, stream,
                     dwb, bng, bnb, bnm, bnv, pww, pwb, rew, reb, vng, vnb,
                     vnm, vnv, outw, smalls, vsum, lsum, wh, wl);
  hipLaunchKernelGGL(kqkv, dim3(2048), dim3(256), 0, stream,
                     x, dww, smalls, qb, kb, vb);
  hipLaunchKernelGGL(kvtrans, dim3(1024), dim3(256), 0, stream, vb, vt, vsum);
  hipLaunchKernelGGL(kl, dim3(256), dim3(512), 0, stream, qb, kb, lsum);
  hipLaunchKernelGGL(kattn2, dim3(512), dim3(512), 0, stream,
                     qb, kb, vt, smalls, vsum, lsum, ohi, olo);
  hipLaunchKernelGGL(kout, dim3(64, 8), dim3(256), 0, stream,
                     ohi, olo, wh, wl, outb, (float*)d_out);
}